// Round 1
// baseline (367.180 us; speedup 1.0000x reference)
//
#include <hip/hip_runtime.h>
#include <hip/hip_bf16.h>

#define RELS 7
#define DIM 64

typedef __attribute__((ext_vector_type(8))) short short8;
typedef __attribute__((ext_vector_type(4))) float floatx4;

__device__ inline unsigned short f2b(float f) {
  union { float f; unsigned u; } v; v.f = f;
  unsigned u = v.u + 0x7fffu + ((v.u >> 16) & 1u);  // round-nearest-even
  return (unsigned short)(u >> 16);
}

// Pass 1: one wave per edge; lane = feature channel.
// acc[dst][rel][d] += x[src][d];  cnt[dst][rel] += 1
__global__ void __launch_bounds__(256) k_scatter(
    const float* __restrict__ x, const int* __restrict__ ei,
    const int* __restrict__ et, float* __restrict__ acc,
    float* __restrict__ cnt, int E)
{
  int e = (int)((blockIdx.x * 256 + threadIdx.x) >> 6);
  int lane = threadIdx.x & 63;
  if (e >= E) return;
  int s = ei[e];
  int d = ei[E + e];
  int r = et[e];
  float v = x[(long)s * DIM + lane];
  atomicAdd(&acc[((long)d * RELS + r) * DIM + lane], v);
  if (lane == 0) atomicAdd(&cnt[d * RELS + r], 1.0f);
}

__global__ void __launch_bounds__(256) k_recip(float* cnt, int n) {
  int i = blockIdx.x * 256 + threadIdx.x;
  if (i < n) cnt[i] = 1.0f / fmaxf(cnt[i], 1.0f);
}

// Pass 3: out[i][:] = sum_r (acc[i][r]/cnt[i][r]) @ W_r + x[i] @ root + bias
// == A @ Bext where A = [means | x]  (K = 8*64 = 512), Bext = [W ; root].
// Bext staged in LDS as bf16, swizzled to MFMA fragment order:
//   group g = (k>>3)*64 + col holds 8 bf16 {B[kb*8+j][col]} -> one ds_read_b128.
__global__ void __launch_bounds__(256) k_gemm(
    const float* __restrict__ acc, const float* __restrict__ invc,
    const float* __restrict__ x, const float* __restrict__ W,
    const float* __restrict__ root, const float* __restrict__ bias,
    float* __restrict__ out, int N)
{
  __shared__ short Bl[512 * DIM];  // 64 KiB
  const int tid = threadIdx.x;

  for (int g = tid; g < 4096; g += 256) {
    int kb = g >> 6, col = g & 63;
    short8 tmp;
#pragma unroll
    for (int j = 0; j < 8; ++j) {
      int k = kb * 8 + j;
      float w = (k < 448) ? W[k * 64 + col] : root[(k - 448) * 64 + col];
      tmp[j] = (short)f2b(w);
    }
    *reinterpret_cast<short8*>(&Bl[g * 8]) = tmp;
  }
  __syncthreads();

  const int lane = tid & 63;
  const int wv = tid >> 6;                 // wave 0..3 -> 16-row strip each
  const int rowbase = blockIdx.x * 64 + wv * 16;
  const int row16 = lane & 15;             // A row within tile / B col within tile
  const int kg = lane >> 4;                // k-group 0..3
  int i = rowbase + row16;
  if (i > N - 1) i = N - 1;                // clamp: loads valid, stores guarded

  floatx4 c0 = {0,0,0,0}, c1 = {0,0,0,0}, c2 = {0,0,0,0}, c3 = {0,0,0,0};
  const short8* Bv = reinterpret_cast<const short8*>(Bl);

#pragma unroll
  for (int kk = 0; kk < 16; ++kk) {        // K = 512, 32 per step
    const int r = kk >> 1;                 // relation (uniform per step)
    const int d0 = (kk * 32 + kg * 8) & 63;
    const float* ap;
    float s;
    if (r < RELS) {
      ap = acc + ((long)i * RELS + r) * DIM + d0;
      s = invc[i * RELS + r];
    } else {                               // "relation 7" = root @ x
      ap = x + (long)i * DIM + d0;
      s = 1.0f;
    }
    float4 f0 = *reinterpret_cast<const float4*>(ap);
    float4 f1 = *reinterpret_cast<const float4*>(ap + 4);
    short8 a;
    a[0] = (short)f2b(f0.x * s); a[1] = (short)f2b(f0.y * s);
    a[2] = (short)f2b(f0.z * s); a[3] = (short)f2b(f0.w * s);
    a[4] = (short)f2b(f1.x * s); a[5] = (short)f2b(f1.y * s);
    a[6] = (short)f2b(f1.z * s); a[7] = (short)f2b(f1.w * s);

    const int bb = (kk * 4 + kg) * 64 + row16;
    c0 = __builtin_amdgcn_mfma_f32_16x16x32_bf16(a, Bv[bb],      c0, 0, 0, 0);
    c1 = __builtin_amdgcn_mfma_f32_16x16x32_bf16(a, Bv[bb + 16], c1, 0, 0, 0);
    c2 = __builtin_amdgcn_mfma_f32_16x16x32_bf16(a, Bv[bb + 32], c2, 0, 0, 0);
    c3 = __builtin_amdgcn_mfma_f32_16x16x32_bf16(a, Bv[bb + 48], c3, 0, 0, 0);
  }

  // D layout: col = lane&15, row = (lane>>4)*4 + reg   [m89-verified]
  const int rowoff = kg * 4;
#pragma unroll
  for (int t = 0; t < 4; ++t) {
    floatx4 c = (t == 0) ? c0 : (t == 1) ? c1 : (t == 2) ? c2 : c3;
    const int col = t * 16 + row16;
    const float b = bias[col];
#pragma unroll
    for (int q = 0; q < 4; ++q) {
      int row = rowbase + rowoff + q;
      if (row < N) out[(long)row * DIM + col] = c[q] + b;
    }
  }
}

extern "C" void kernel_launch(void* const* d_in, const int* in_sizes, int n_in,
                              void* d_out, int out_size, void* d_ws, size_t ws_size,
                              hipStream_t stream)
{
  const float* x    = (const float*)d_in[0];
  const float* W    = (const float*)d_in[1];   // [7][64][64] == [448][64]
  const float* root = (const float*)d_in[2];   // [64][64]
  const float* bias = (const float*)d_in[3];   // [64]
  const int*   ei   = (const int*)d_in[4];     // [2][E]
  const int*   et   = (const int*)d_in[5];     // [E]
  float* out = (float*)d_out;

  const int N = in_sizes[0] / DIM;
  const int E = in_sizes[4] / 2;

  // workspace: acc f32 [N][7][64] (179.2 MB) + cnt f32 [N][7] (2.8 MB)
  float* acc = (float*)d_ws;
  float* cnt = acc + (size_t)N * RELS * DIM;
  size_t zbytes = ((size_t)N * RELS * DIM + (size_t)N * RELS) * sizeof(float);
  hipMemsetAsync(d_ws, 0, zbytes, stream);

  int sblocks = (int)(((long)E * 64 + 255) / 256);
  k_scatter<<<sblocks, 256, 0, stream>>>(x, ei, et, acc, cnt, E);
  k_recip<<<(N * RELS + 255) / 256, 256, 0, stream>>>(cnt, N * RELS);
  int gblocks = (N + 63) / 64;
  k_gemm<<<gblocks, 256, 0, stream>>>(acc, cnt, x, W, root, bias, out, N);
}

// Round 2
// 300.089 us; speedup vs baseline: 1.2236x; 1.2236x over previous
//
#include <hip/hip_runtime.h>
#include <hip/hip_bf16.h>

#define RELS 7
#define DIM 64
#define KTOT 512  // 7*64 + 64 (root)

typedef __attribute__((ext_vector_type(8))) short short8;
typedef __attribute__((ext_vector_type(4))) float floatx4;

__device__ inline unsigned short f2b(float f) {
  union { float f; unsigned u; } v; v.f = f;
  unsigned u = v.u + 0x7fffu + ((v.u >> 16) & 1u);  // round-nearest-even
  return (unsigned short)(u >> 16);
}
__device__ inline float b2f(unsigned short b) {
  union { unsigned u; float f; } v; v.u = ((unsigned)b) << 16;
  return v.f;
}

// x f32 -> bf16 (8 elems/thread)
__global__ void __launch_bounds__(256) k_xb(const float* __restrict__ x,
                                            unsigned short* __restrict__ xb, long n8) {
  long t = (long)blockIdx.x * 256 + threadIdx.x;
  if (t >= n8) return;
  const float4* p = reinterpret_cast<const float4*>(x + t * 8);
  float4 f0 = p[0], f1 = p[1];
  short8 o;
  o[0] = (short)f2b(f0.x); o[1] = (short)f2b(f0.y);
  o[2] = (short)f2b(f0.z); o[3] = (short)f2b(f0.w);
  o[4] = (short)f2b(f1.x); o[5] = (short)f2b(f1.y);
  o[6] = (short)f2b(f1.z); o[7] = (short)f2b(f1.w);
  *reinterpret_cast<short8*>(xb + t * 8) = o;
}

__global__ void __launch_bounds__(256) k_hist(const int* __restrict__ dst,
                                              int* __restrict__ deg, int E) {
  int e = blockIdx.x * 256 + threadIdx.x;
  if (e < E) atomicAdd(&deg[dst[e]], 1);
}

// block-local exclusive scan over 1024 entries (256 thr x 4)
__global__ void __launch_bounds__(256) k_scan1(const int* __restrict__ deg,
                                               int* __restrict__ start,
                                               int* __restrict__ bsum, int n) {
  __shared__ int sm[256];
  int t = threadIdx.x;
  int base = blockIdx.x * 1024 + t * 4;
  int v0 = (base + 0 < n) ? deg[base + 0] : 0;
  int v1 = (base + 1 < n) ? deg[base + 1] : 0;
  int v2 = (base + 2 < n) ? deg[base + 2] : 0;
  int v3 = (base + 3 < n) ? deg[base + 3] : 0;
  int s = v0 + v1 + v2 + v3;
  sm[t] = s;
  __syncthreads();
  for (int off = 1; off < 256; off <<= 1) {
    int a = (t >= off) ? sm[t - off] : 0;
    __syncthreads();
    sm[t] += a;
    __syncthreads();
  }
  int excl = sm[t] - s;
  if (base + 0 < n) start[base + 0] = excl;
  excl += v0;
  if (base + 1 < n) start[base + 1] = excl;
  excl += v1;
  if (base + 2 < n) start[base + 2] = excl;
  excl += v2;
  if (base + 3 < n) start[base + 3] = excl;
  if (t == 255) bsum[blockIdx.x] = sm[255];
}

__global__ void __launch_bounds__(128) k_scan2(int* bsum, int nb) {
  __shared__ int sm[128];
  int t = threadIdx.x;
  int v = (t < nb) ? bsum[t] : 0;
  sm[t] = v;
  __syncthreads();
  for (int off = 1; off < 128; off <<= 1) {
    int a = (t >= off) ? sm[t - off] : 0;
    __syncthreads();
    sm[t] += a;
    __syncthreads();
  }
  if (t < nb) bsum[t] = sm[t] - v;  // exclusive block offset
}

__global__ void __launch_bounds__(256) k_scan3(int* __restrict__ start,
                                               int* __restrict__ cursor,
                                               const int* __restrict__ bsum,
                                               int n, int E) {
  int i = blockIdx.x * 256 + threadIdx.x;
  if (i < n) {
    int v = start[i] + bsum[i >> 10];
    start[i] = v;
    cursor[i] = v;
  } else if (i == n) {
    start[n] = E;
  }
}

__global__ void __launch_bounds__(256) k_bucket(const int* __restrict__ ei,
                                                const int* __restrict__ et,
                                                int* __restrict__ cursor,
                                                int* __restrict__ esrc, int E) {
  int e = blockIdx.x * 256 + threadIdx.x;
  if (e >= E) return;
  int s = ei[e], d = ei[E + e], r = et[e];
  int pos = atomicAdd(&cursor[d], 1);
  esrc[pos] = s | (r << 17);  // N < 2^17, r < 8
}

// one wave per dst node: per-relation mean of gathered bf16 x rows
__global__ void __launch_bounds__(256) k_seg(const int* __restrict__ start,
                                             const int* __restrict__ esrc,
                                             const unsigned short* __restrict__ xb,
                                             unsigned short* __restrict__ mn, int N) {
  int w = (int)((blockIdx.x * 256 + threadIdx.x) >> 6);
  int lane = threadIdx.x & 63;
  if (w >= N) return;
  int a = start[w], b = start[w + 1];
  float a0 = 0, a1 = 0, a2 = 0, a3 = 0, a4 = 0, a5 = 0, a6 = 0;
  float c0 = 0, c1 = 0, c2 = 0, c3 = 0, c4 = 0, c5 = 0, c6 = 0;
  for (int e = a; e < b; ++e) {
    int v = esrc[e];
    int src = v & 0x1FFFF;
    int r = v >> 17;
    float f = b2f(xb[(long)src * DIM + lane]);
    a0 += (r == 0) ? f : 0.0f; c0 += (r == 0) ? 1.0f : 0.0f;
    a1 += (r == 1) ? f : 0.0f; c1 += (r == 1) ? 1.0f : 0.0f;
    a2 += (r == 2) ? f : 0.0f; c2 += (r == 2) ? 1.0f : 0.0f;
    a3 += (r == 3) ? f : 0.0f; c3 += (r == 3) ? 1.0f : 0.0f;
    a4 += (r == 4) ? f : 0.0f; c4 += (r == 4) ? 1.0f : 0.0f;
    a5 += (r == 5) ? f : 0.0f; c5 += (r == 5) ? 1.0f : 0.0f;
    a6 += (r == 6) ? f : 0.0f; c6 += (r == 6) ? 1.0f : 0.0f;
  }
  long o = (long)w * (RELS * DIM) + lane;
  mn[o + 0 * DIM] = f2b(a0 / fmaxf(c0, 1.0f));
  mn[o + 1 * DIM] = f2b(a1 / fmaxf(c1, 1.0f));
  mn[o + 2 * DIM] = f2b(a2 / fmaxf(c2, 1.0f));
  mn[o + 3 * DIM] = f2b(a3 / fmaxf(c3, 1.0f));
  mn[o + 4 * DIM] = f2b(a4 / fmaxf(c4, 1.0f));
  mn[o + 5 * DIM] = f2b(a5 / fmaxf(c5, 1.0f));
  mn[o + 6 * DIM] = f2b(a6 / fmaxf(c6, 1.0f));
}

// out[i][:] = [mn[i] | xb[i]] (K=512, bf16) @ [W;root] + bias
__global__ void __launch_bounds__(256) k_gemm(const unsigned short* __restrict__ mn,
                                              const unsigned short* __restrict__ xb,
                                              const float* __restrict__ W,
                                              const float* __restrict__ root,
                                              const float* __restrict__ bias,
                                              float* __restrict__ out, int N)
{
  __shared__ short Bl[KTOT * DIM];  // 64 KiB, MFMA-fragment order
  const int tid = threadIdx.x;

  for (int g = tid; g < 4096; g += 256) {
    int kb = g >> 6, col = g & 63;
    short8 tmp;
#pragma unroll
    for (int j = 0; j < 8; ++j) {
      int k = kb * 8 + j;
      float w = (k < 448) ? W[k * 64 + col] : root[(k - 448) * 64 + col];
      tmp[j] = (short)f2b(w);
    }
    *reinterpret_cast<short8*>(&Bl[g * 8]) = tmp;
  }
  __syncthreads();

  const int lane = tid & 63;
  const int wv = tid >> 6;
  const int rowbase = blockIdx.x * 64 + wv * 16;
  const int row16 = lane & 15;
  const int kg = lane >> 4;
  int i = rowbase + row16;
  if (i > N - 1) i = N - 1;

  floatx4 c0 = {0,0,0,0}, c1 = {0,0,0,0}, c2 = {0,0,0,0}, c3 = {0,0,0,0};
  const short8* Bv = reinterpret_cast<const short8*>(Bl);

#pragma unroll
  for (int kk = 0; kk < 16; ++kk) {
    const int r = kk >> 1;
    const int d0 = (kk * 32 + kg * 8) & 63;
    const unsigned short* ap = (r < RELS)
        ? (mn + (long)i * (RELS * DIM) + r * DIM + d0)
        : (xb + (long)i * DIM + d0);
    short8 aa = *reinterpret_cast<const short8*>(ap);
    const int bb = (kk * 4 + kg) * 64 + row16;
    c0 = __builtin_amdgcn_mfma_f32_16x16x32_bf16(aa, Bv[bb],      c0, 0, 0, 0);
    c1 = __builtin_amdgcn_mfma_f32_16x16x32_bf16(aa, Bv[bb + 16], c1, 0, 0, 0);
    c2 = __builtin_amdgcn_mfma_f32_16x16x32_bf16(aa, Bv[bb + 32], c2, 0, 0, 0);
    c3 = __builtin_amdgcn_mfma_f32_16x16x32_bf16(aa, Bv[bb + 48], c3, 0, 0, 0);
  }

  const int rowoff = kg * 4;
#pragma unroll
  for (int t = 0; t < 4; ++t) {
    floatx4 c = (t == 0) ? c0 : (t == 1) ? c1 : (t == 2) ? c2 : c3;
    const int col = t * 16 + row16;
    const float b = bias[col];
#pragma unroll
    for (int q = 0; q < 4; ++q) {
      int row = rowbase + rowoff + q;
      if (row < N) out[(long)row * DIM + col] = c[q] + b;
    }
  }
}

extern "C" void kernel_launch(void* const* d_in, const int* in_sizes, int n_in,
                              void* d_out, int out_size, void* d_ws, size_t ws_size,
                              hipStream_t stream)
{
  const float* x    = (const float*)d_in[0];
  const float* W    = (const float*)d_in[1];
  const float* root = (const float*)d_in[2];
  const float* bias = (const float*)d_in[3];
  const int*   ei   = (const int*)d_in[4];
  const int*   et   = (const int*)d_in[5];
  float* out = (float*)d_out;

  const int N = in_sizes[0] / DIM;
  const int E = in_sizes[4] / 2;

  // workspace layout
  unsigned short* mn = (unsigned short*)d_ws;            // [N][7][64] bf16
  unsigned short* xb = mn + (size_t)N * RELS * DIM;      // [N][64] bf16
  int* esrc   = (int*)(xb + (size_t)N * DIM);            // [E]
  int* deg    = esrc + E;                                // [N]
  int* start  = deg + N;                                 // [N+1]
  int* cursor = start + N + 1;                           // [N]
  int* bsum   = cursor + N;                              // [ceil(N/1024)]

  hipMemsetAsync(deg, 0, (size_t)N * sizeof(int), stream);
  k_xb<<<(int)(((long)N * DIM / 8 + 255) / 256), 256, 0, stream>>>(x, xb, (long)N * DIM / 8);
  k_hist<<<(E + 255) / 256, 256, 0, stream>>>(ei + E, deg, E);
  int nb = (N + 1023) / 1024;
  k_scan1<<<nb, 256, 0, stream>>>(deg, start, bsum, N);
  k_scan2<<<1, 128, 0, stream>>>(bsum, nb);
  k_scan3<<<(N + 1 + 255) / 256, 256, 0, stream>>>(start, cursor, bsum, N, E);
  k_bucket<<<(E + 255) / 256, 256, 0, stream>>>(ei, et, cursor, esrc, E);
  k_seg<<<(int)(((long)N * 64 + 255) / 256), 256, 0, stream>>>(start, esrc, xb, mn, N);
  k_gemm<<<(N + 63) / 64, 256, 0, stream>>>(mn, xb, W, root, bias, out, N);
}